// Round 2
// baseline (536.216 us; speedup 1.0000x reference)
//
#include <hip/hip_runtime.h>
#include <hip/hip_bf16.h>

// Problem constants (fixed by the reference):
//   h: (T=32, BN=16384, C=128) f32; w_real/w_imag: (128,128,3) f32.
// Math: only rfft modes 0..2 survive ->
//   X_m[b,i] = sum_t h[t,b,i] * exp(-i*2pi*m*t/32)       (5 real planes; X0 real)
//   Y_m[b,o] = sum_i X_m[b,i] * w[i,o,m]                 (Im(Y0) discarded by irfft)
//   y[t,b,o] = Y0/32 + (Y1re*cos(wt)-Y1im*sin(wt))/16 + (Y2re*cos(2wt)-Y2im*sin(2wt))/16
//   out = h + leaky_relu(y, 0.2)

#define T 32
#define BN 16384
#define C 128
#define NBC (BN * C) /* 2097152 */

typedef __attribute__((ext_vector_type(4))) float f32x4;
typedef __attribute__((ext_vector_type(8))) short bf16x8;
typedef __attribute__((ext_vector_type(4))) unsigned short u16x4;

__constant__ float COS32[32] = {
    1.0f,           0.9807852804f,  0.9238795325f,  0.8314696123f,
    0.7071067812f,  0.5555702330f,  0.3826834324f,  0.1950903220f,
    0.0f,          -0.1950903220f, -0.3826834324f, -0.5555702330f,
   -0.7071067812f, -0.8314696123f, -0.9238795325f, -0.9807852804f,
   -1.0f,          -0.9807852804f, -0.9238795325f, -0.8314696123f,
   -0.7071067812f, -0.5555702330f, -0.3826834324f, -0.1950903220f,
    0.0f,           0.1950903220f,  0.3826834324f,  0.5555702330f,
    0.7071067812f,  0.8314696123f,  0.9238795325f,  0.9807852804f};

__constant__ float SIN32[32] = {
    0.0f,           0.1950903220f,  0.3826834324f,  0.5555702330f,
    0.7071067812f,  0.8314696123f,  0.9238795325f,  0.9807852804f,
    1.0f,           0.9807852804f,  0.9238795325f,  0.8314696123f,
    0.7071067812f,  0.5555702330f,  0.3826834324f,  0.1950903220f,
    0.0f,          -0.1950903220f, -0.3826834324f, -0.5555702330f,
   -0.7071067812f, -0.8314696123f, -0.9238795325f, -0.9807852804f,
   -1.0f,          -0.9807852804f, -0.9238795325f, -0.8314696123f,
   -0.7071067812f, -0.5555702330f, -0.3826834324f, -0.1950903220f};

__device__ __forceinline__ unsigned short f2bf(float f) {
    unsigned x = __float_as_uint(f);
    x += 0x7fffu + ((x >> 16) & 1u); // round-to-nearest-even
    return (unsigned short)(x >> 16);
}

__device__ __forceinline__ bf16x8 bfneg(bf16x8 a) {
    bf16x8 r;
#pragma unroll
    for (int i = 0; i < 8; ++i) r[i] = (short)(a[i] ^ (short)0x8000);
    return r;
}

// ---------------------------------------------------------------------------
// K0: pre-pack W (f32, layout (i,o,m)) into bf16 MFMA B-fragments.
// comp: 0=W0re 1=W1re 2=W1im 3=W2re 4=W2im
// Wfrag layout: [comp][nt(8)][kk(4)][lane(64)][8 bf16]
// B-operand layout for mfma_f32_16x16x32_bf16: col = lane&15, k = (lane>>4)*8 + j
// ---------------------------------------------------------------------------
__global__ __launch_bounds__(256) void k_wfrag(const float* __restrict__ wr,
                                               const float* __restrict__ wi,
                                               unsigned short* __restrict__ Wfrag) {
    int tid = blockIdx.x * 256 + threadIdx.x; // exactly 10240 threads
    int lane = tid & 63;
    int kk = (tid >> 6) & 3;
    int nt = (tid >> 8) & 7;
    int comp = tid >> 11; // 0..4
    const float* src = (comp == 2 || comp == 4) ? wi : wr;
    int m = (comp == 0) ? 0 : ((comp <= 2) ? 1 : 2);
    int o = nt * 16 + (lane & 15);
    int kb = kk * 32 + (lane >> 4) * 8;
    unsigned short v[8];
#pragma unroll
    for (int j = 0; j < 8; ++j)
        v[j] = f2bf(src[(size_t)((kb + j) * C + o) * 3 + m]);
    u16x4* dst = (u16x4*)(Wfrag + (size_t)tid * 8);
    u16x4 lo = {v[0], v[1], v[2], v[3]};
    u16x4 hi = {v[4], v[5], v[6], v[7]};
    dst[0] = lo;
    dst[1] = hi;
}

// ---------------------------------------------------------------------------
// K1: X-planes. One thread per 4 consecutive (b,c) flat elements.
// Xb layout: [comp(5)][b(16384)][i(128)] bf16, comp as above (X planes).
// ---------------------------------------------------------------------------
__global__ __launch_bounds__(256) void k_xmodes(const float* __restrict__ h,
                                                unsigned short* __restrict__ Xb) {
    int idx4 = blockIdx.x * 256 + threadIdx.x; // 0 .. NBC/4-1
    const f32x4* hp = (const f32x4*)h + idx4;
    f32x4 z = {0.f, 0.f, 0.f, 0.f};
    f32x4 x0 = z, x1r = z, x1i = z, x2r = z, x2i = z;
#pragma unroll
    for (int t = 0; t < T; ++t) {
        f32x4 v = hp[(size_t)t * (NBC / 4)];
        float c1 = COS32[t], s1 = SIN32[t];
        float c2 = COS32[(2 * t) & 31], s2 = SIN32[(2 * t) & 31];
        x0 += v;
        x1r += v * c1;
        x1i -= v * s1;
        x2r += v * c2;
        x2i -= v * s2;
    }
    f32x4 xs[5] = {x0, x1r, x1i, x2r, x2i};
#pragma unroll
    for (int c = 0; c < 5; ++c) {
        u16x4 o = {f2bf(xs[c][0]), f2bf(xs[c][1]), f2bf(xs[c][2]), f2bf(xs[c][3])};
        *(u16x4*)(Xb + (size_t)c * NBC + (size_t)idx4 * 4) = o;
    }
}

// ---------------------------------------------------------------------------
// K2: 9 GEMMs [16384x128]x[128x128] via mfma_f32_16x16x32_bf16.
// Block = 256 thr = 4 waves; block owns 64 rows (b) x 64 out-cols (nt half).
// grid = 512: blockIdx.x>>1 = row group, blockIdx.x&1 = nt half (occupancy:
// 2 blocks/CU = 8 waves/CU; A-fragments re-read once more from L2/L3, ~free).
// A-operand layout: row = lane&15, k = (lane>>4)*8 + j  (contiguous in i).
// Y layout: [comp(5)][b][o] f32. comp: 0=Y0re 1=Y1re 2=Y1im 3=Y2re 4=Y2im
// ---------------------------------------------------------------------------
__global__ __launch_bounds__(256) void k_gemm(const unsigned short* __restrict__ Wfrag,
                                              const unsigned short* __restrict__ Xb,
                                              float* __restrict__ Y) {
    const int wave = threadIdx.x >> 6;
    const int lane = threadIdx.x & 63;
    const int arow = lane & 15;
    const int kgrp = lane >> 4;
    const int mbase = (blockIdx.x >> 1) * 64 + wave * 16;
    const int ntb = (blockIdx.x & 1) * 4;

    bf16x8 A[5][4];
    const unsigned short* xp = Xb + (size_t)(mbase + arow) * C + kgrp * 8;
#pragma unroll
    for (int c = 0; c < 5; ++c)
#pragma unroll
        for (int kk = 0; kk < 4; ++kk)
            A[c][kk] = *(const bf16x8*)(xp + (size_t)c * NBC + kk * 32);

    bf16x8 nA1[4], nA2[4];
#pragma unroll
    for (int kk = 0; kk < 4; ++kk) {
        nA1[kk] = bfneg(A[2][kk]); // -X1im
        nA2[kk] = bfneg(A[4][kk]); // -X2im
    }

    const bf16x8* wf = (const bf16x8*)Wfrag;
#pragma unroll
    for (int nto = 0; nto < 4; ++nto) {
        const int nt = ntb + nto;
        f32x4 z = {0.f, 0.f, 0.f, 0.f};
        f32x4 acc0 = z, acc1 = z, acc2 = z, acc3 = z, acc4 = z;
#pragma unroll
        for (int kk = 0; kk < 4; ++kk) {
            bf16x8 B0  = wf[(size_t)(((0 * 8 + nt) * 4 + kk) * 64) + lane];
            bf16x8 B1r = wf[(size_t)(((1 * 8 + nt) * 4 + kk) * 64) + lane];
            bf16x8 B1i = wf[(size_t)(((2 * 8 + nt) * 4 + kk) * 64) + lane];
            bf16x8 B2r = wf[(size_t)(((3 * 8 + nt) * 4 + kk) * 64) + lane];
            bf16x8 B2i = wf[(size_t)(((4 * 8 + nt) * 4 + kk) * 64) + lane];
            acc0 = __builtin_amdgcn_mfma_f32_16x16x32_bf16(A[0][kk], B0, acc0, 0, 0, 0);
            acc1 = __builtin_amdgcn_mfma_f32_16x16x32_bf16(A[1][kk], B1r, acc1, 0, 0, 0);
            acc1 = __builtin_amdgcn_mfma_f32_16x16x32_bf16(nA1[kk], B1i, acc1, 0, 0, 0);
            acc2 = __builtin_amdgcn_mfma_f32_16x16x32_bf16(A[1][kk], B1i, acc2, 0, 0, 0);
            acc2 = __builtin_amdgcn_mfma_f32_16x16x32_bf16(A[2][kk], B1r, acc2, 0, 0, 0);
            acc3 = __builtin_amdgcn_mfma_f32_16x16x32_bf16(A[3][kk], B2r, acc3, 0, 0, 0);
            acc3 = __builtin_amdgcn_mfma_f32_16x16x32_bf16(nA2[kk], B2i, acc3, 0, 0, 0);
            acc4 = __builtin_amdgcn_mfma_f32_16x16x32_bf16(A[3][kk], B2i, acc4, 0, 0, 0);
            acc4 = __builtin_amdgcn_mfma_f32_16x16x32_bf16(A[4][kk], B2r, acc4, 0, 0, 0);
        }
        // C/D layout (verified, guide m89): col = lane&15, row = (lane>>4)*4 + r
        const int orow = mbase + kgrp * 4;
        const int ocol = nt * 16 + arow;
#pragma unroll
        for (int r = 0; r < 4; ++r) {
            size_t off = (size_t)(orow + r) * C + ocol;
            Y[(size_t)0 * NBC + off] = acc0[r];
            Y[(size_t)1 * NBC + off] = acc1[r];
            Y[(size_t)2 * NBC + off] = acc2[r];
            Y[(size_t)3 * NBC + off] = acc3[r];
            Y[(size_t)4 * NBC + off] = acc4[r];
        }
    }
}

// ---------------------------------------------------------------------------
// K3: reconstruct y[t,b,o] from 5 Y values, fuse residual + leaky ReLU.
// One thread per 4 consecutive (b,o) elements; loops over all 32 t.
// ---------------------------------------------------------------------------
__global__ __launch_bounds__(256) void k_recon(const float* __restrict__ Y,
                                               const float* __restrict__ h,
                                               float* __restrict__ out) {
    int idx4 = blockIdx.x * 256 + threadIdx.x; // 0 .. NBC/4-1
    const f32x4* Yp = (const f32x4*)Y;
    f32x4 y0 = Yp[(size_t)0 * (NBC / 4) + idx4] * (1.f / 32.f);
    f32x4 y1r = Yp[(size_t)1 * (NBC / 4) + idx4] * (1.f / 16.f);
    f32x4 y1i = Yp[(size_t)2 * (NBC / 4) + idx4] * (1.f / 16.f);
    f32x4 y2r = Yp[(size_t)3 * (NBC / 4) + idx4] * (1.f / 16.f);
    f32x4 y2i = Yp[(size_t)4 * (NBC / 4) + idx4] * (1.f / 16.f);
    const f32x4* hp = (const f32x4*)h + idx4;
    f32x4* op = (f32x4*)out + idx4;
#pragma unroll
    for (int t = 0; t < T; ++t) {
        float c1 = COS32[t], s1 = SIN32[t];
        float c2 = COS32[(2 * t) & 31], s2 = SIN32[(2 * t) & 31];
        f32x4 y = y0 + c1 * y1r - s1 * y1i + c2 * y2r - s2 * y2i;
        f32x4 hv = hp[(size_t)t * (NBC / 4)];
        f32x4 r;
#pragma unroll
        for (int j = 0; j < 4; ++j) {
            float v = y[j];
            r[j] = hv[j] + fmaxf(v, 0.f) + 0.2f * fminf(v, 0.f);
        }
        op[(size_t)t * (NBC / 4)] = r;
    }
}

// ---------------------------------------------------------------------------
// Workspace layout (requires ws_size >= 61 MiB):
//   [0, 160KB)            Wfrag (bf16 fragments)
//   [1MiB, 21MiB)         Xb: 5 planes x 2M bf16
//   [21MiB, 61MiB)        Y : 5 planes x 2M f32
// ---------------------------------------------------------------------------
extern "C" void kernel_launch(void* const* d_in, const int* in_sizes, int n_in,
                              void* d_out, int out_size, void* d_ws, size_t ws_size,
                              hipStream_t stream) {
    const float* h = (const float*)d_in[0];
    const float* wr = (const float*)d_in[1];
    const float* wi = (const float*)d_in[2];
    float* out = (float*)d_out;
    char* ws = (char*)d_ws;
    unsigned short* Wfrag = (unsigned short*)ws;
    unsigned short* Xb = (unsigned short*)(ws + (1u << 20));
    float* Y = (float*)(ws + (1u << 20) + (size_t)5 * NBC * 2);

    k_wfrag<<<40, 256, 0, stream>>>(wr, wi, Wfrag);
    k_xmodes<<<NBC / 1024, 256, 0, stream>>>(h, Xb);
    k_gemm<<<BN / 128, 256, 0, stream>>>(Wfrag, Xb, Y);
    k_recon<<<NBC / 1024, 256, 0, stream>>>(Y, h, out);
}

// Round 5
// 475.746 us; speedup vs baseline: 1.1271x; 1.1271x over previous
//
#include <hip/hip_runtime.h>

// TimeConv: h (32,16384,128) f32; w_real/w_imag (128,128,3) f32.
// Only rfft modes 0..2 survive:
//   X_m[b,i] = sum_t h[t,b,i] e^{-i 2pi m t/32}   (5 real planes; Im(X0)=0)
//   Y_m[b,o] = sum_i X_m[b,i] w[i,o,m]            (Im(Y0) discarded by irfft)
//   y[t,b,o] = Y0/32 + (Y1re c1 - Y1im s1)/16 + (Y2re c2 - Y2im s2)/16
//   out = h + leaky_relu(y, 0.2)
// Scales 1/32, 1/16 are folded into the packed W fragments.

#define T 32
#define BN 16384
#define C 128
#define NBC (BN * C)   /* 2097152 */
#define NBC4 (NBC / 4) /* 524288  */

typedef __attribute__((ext_vector_type(4))) float f32x4;
typedef __attribute__((ext_vector_type(8))) short bf16x8;
typedef __attribute__((ext_vector_type(4))) unsigned short u16x4;

__constant__ float COS32[32] = {
    1.0f,           0.9807852804f,  0.9238795325f,  0.8314696123f,
    0.7071067812f,  0.5555702330f,  0.3826834324f,  0.1950903220f,
    0.0f,          -0.1950903220f, -0.3826834324f, -0.5555702330f,
   -0.7071067812f, -0.8314696123f, -0.9238795325f, -0.9807852804f,
   -1.0f,          -0.9807852804f, -0.9238795325f, -0.8314696123f,
   -0.7071067812f, -0.5555702330f, -0.3826834324f, -0.1950903220f,
    0.0f,           0.1950903220f,  0.3826834324f,  0.5555702330f,
    0.7071067812f,  0.8314696123f,  0.9238795325f,  0.9807852804f};

__constant__ float SIN32[32] = {
    0.0f,           0.1950903220f,  0.3826834324f,  0.5555702330f,
    0.7071067812f,  0.8314696123f,  0.9238795325f,  0.9807852804f,
    1.0f,           0.9807852804f,  0.9238795325f,  0.8314696123f,
    0.7071067812f,  0.5555702330f,  0.3826834324f,  0.1950903220f,
    0.0f,          -0.1950903220f, -0.3826834324f, -0.5555702330f,
   -0.7071067812f, -0.8314696123f, -0.9238795325f, -0.9807852804f,
   -1.0f,          -0.9807852804f, -0.9238795325f, -0.8314696123f,
   -0.7071067812f, -0.5555702330f, -0.3826834324f, -0.1950903220f};

__device__ __forceinline__ unsigned short f2bf(float f) {
    unsigned x = __float_as_uint(f);
    x += 0x7fffu + ((x >> 16) & 1u); // RNE
    return (unsigned short)(x >> 16);
}

__device__ __forceinline__ bf16x8 bfneg(bf16x8 a) {
    bf16x8 r;
#pragma unroll
    for (int i = 0; i < 8; ++i) r[i] = (short)(a[i] ^ (short)0x8000);
    return r;
}

// ---------------------------------------------------------------------------
// K0: pack W into bf16 MFMA B-fragments, folding the irfft scale.
// comp: 0=W0re/32 1=W1re/16 2=W1im/16 3=W2re/16 4=W2im/16
// Wfrag layout: [comp][nt(8)][kk(4)][lane(64)][8 bf16]  (160 KiB)
// B-operand (16x16x32 bf16): col = lane&15, k = (lane>>4)*8 + j
// ---------------------------------------------------------------------------
__global__ __launch_bounds__(256) void k_wfrag(const float* __restrict__ wr,
                                               const float* __restrict__ wi,
                                               unsigned short* __restrict__ Wfrag) {
    int tid = blockIdx.x * 256 + threadIdx.x; // exactly 10240 threads
    int lane = tid & 63;
    int kk = (tid >> 6) & 3;
    int nt = (tid >> 8) & 7;
    int comp = tid >> 11; // 0..4
    const float* src = (comp == 2 || comp == 4) ? wi : wr;
    int m = (comp == 0) ? 0 : ((comp <= 2) ? 1 : 2);
    float sc = (comp == 0) ? 0.03125f : 0.0625f; // 1/32 : 1/16 (exact pow2)
    int o = nt * 16 + (lane & 15);
    int kb = kk * 32 + (lane >> 4) * 8;
    unsigned short v[8];
#pragma unroll
    for (int j = 0; j < 8; ++j)
        v[j] = f2bf(sc * src[(size_t)((kb + j) * C + o) * 3 + m]);
    u16x4* dst = (u16x4*)(Wfrag + (size_t)tid * 8);
    u16x4 lo = {v[0], v[1], v[2], v[3]};
    u16x4 hi = {v[4], v[5], v[6], v[7]};
    dst[0] = lo;
    dst[1] = hi;
}

// ---------------------------------------------------------------------------
// K_main: single fused kernel. Block = 512 thr (8 waves), 8 b-rows per block.
// Thread (row=wv, i4, th): owns h[t in th-half, brow+row, i4*4..+3].
//  A: 16 strided f32x4 loads -> X partials in regs (h STAYS IN REGISTERS).
//     Cross-half reduce via shfl_xor(32); th==0 writes bf16 X frags to xS.
//  B: wave wv computes out-cols [wv*16,+16) via 9 zero-padded M=8 MFMAs
//     per kk; Y (scales pre-folded) staged to yS.
//  C: read 5 y vecs from yS once; 16 t-iters: out = h(reg) + leaky(y).
// LDS: 10K (xS) + 20K (yS) = 30 KiB.
// ---------------------------------------------------------------------------
__global__ __launch_bounds__(512) void k_main(const float* __restrict__ h,
                                              const unsigned short* __restrict__ Wfrag,
                                              float* __restrict__ out) {
    __shared__ float yS[5 * 8 * C];            // 20480 B
    __shared__ unsigned short xS[5 * 8 * C];   // 10240 B

    const int tid = threadIdx.x;
    const int lane = tid & 63;
    const int wv = tid >> 6;        // 0..7: row in A/C, nt in B
    const int i4 = tid & 31;
    const int th = (tid >> 5) & 1;  // t-half
    const int row = wv;
    const int brow = blockIdx.x * 8;
    const int tb = th * 16;

    // ---------------- Phase A ----------------
    const f32x4* hp = (const f32x4*)h + (size_t)(brow + row) * 32 + i4;
    f32x4 v[16];
#pragma unroll
    for (int tt = 0; tt < 16; ++tt) v[tt] = hp[(size_t)(tb + tt) * NBC4];

    f32x4 z = {0.f, 0.f, 0.f, 0.f};
    f32x4 x0 = z, x1r = z, x1i = z, x2r = z, x2i = z;
#pragma unroll
    for (int tt = 0; tt < 16; ++tt) {
        int t = tb + tt;
        float c1 = COS32[t], s1 = SIN32[t];
        float c2 = COS32[(2 * t) & 31], s2 = SIN32[(2 * t) & 31];
        f32x4 hv = v[tt];
        x0 += hv;
        x1r += hv * c1;
        x1i -= hv * s1;
        x2r += hv * c2;
        x2i -= hv * s2;
    }
    f32x4 xs[5] = {x0, x1r, x1i, x2r, x2i};
#pragma unroll
    for (int c = 0; c < 5; ++c)
#pragma unroll
        for (int j = 0; j < 4; ++j) xs[c][j] += __shfl_xor(xs[c][j], 32, 64);
    if (th == 0) {
#pragma unroll
        for (int c = 0; c < 5; ++c) {
            u16x4 o = {f2bf(xs[c][0]), f2bf(xs[c][1]), f2bf(xs[c][2]), f2bf(xs[c][3])};
            *(u16x4*)&xS[(c * 8 + row) * C + i4 * 4] = o;
        }
    }
    __syncthreads();

    // ---------------- Phase B (GEMM) ----------------
    {
        const int arow = lane & 15;
        const int kgrp = lane >> 4;
        const bf16x8* wf = (const bf16x8*)Wfrag;
        f32x4 acc0 = z, acc1 = z, acc2 = z, acc3 = z, acc4 = z;
#pragma unroll
        for (int kk = 0; kk < 4; ++kk) {
            bf16x8 A0 = {0, 0, 0, 0, 0, 0, 0, 0};
            bf16x8 A1 = A0, A2 = A0, A3 = A0, A4 = A0;
            if (arow < 8) {
                const int xo = arow * C + kk * 32 + kgrp * 8;
                A0 = *(const bf16x8*)&xS[(0 * 8) * C + xo];
                A1 = *(const bf16x8*)&xS[(1 * 8) * C + xo];
                A2 = *(const bf16x8*)&xS[(2 * 8) * C + xo];
                A3 = *(const bf16x8*)&xS[(3 * 8) * C + xo];
                A4 = *(const bf16x8*)&xS[(4 * 8) * C + xo];
            }
            bf16x8 nA2v = bfneg(A2); // -X1im
            bf16x8 nA4v = bfneg(A4); // -X2im
            bf16x8 B0  = wf[(size_t)(((0 * 8 + wv) * 4 + kk) * 64) + lane];
            bf16x8 B1r = wf[(size_t)(((1 * 8 + wv) * 4 + kk) * 64) + lane];
            bf16x8 B1i = wf[(size_t)(((2 * 8 + wv) * 4 + kk) * 64) + lane];
            bf16x8 B2r = wf[(size_t)(((3 * 8 + wv) * 4 + kk) * 64) + lane];
            bf16x8 B2i = wf[(size_t)(((4 * 8 + wv) * 4 + kk) * 64) + lane];
            acc0 = __builtin_amdgcn_mfma_f32_16x16x32_bf16(A0, B0, acc0, 0, 0, 0);
            acc1 = __builtin_amdgcn_mfma_f32_16x16x32_bf16(A1, B1r, acc1, 0, 0, 0);
            acc1 = __builtin_amdgcn_mfma_f32_16x16x32_bf16(nA2v, B1i, acc1, 0, 0, 0);
            acc2 = __builtin_amdgcn_mfma_f32_16x16x32_bf16(A1, B1i, acc2, 0, 0, 0);
            acc2 = __builtin_amdgcn_mfma_f32_16x16x32_bf16(A2, B1r, acc2, 0, 0, 0);
            acc3 = __builtin_amdgcn_mfma_f32_16x16x32_bf16(A3, B2r, acc3, 0, 0, 0);
            acc3 = __builtin_amdgcn_mfma_f32_16x16x32_bf16(nA4v, B2i, acc3, 0, 0, 0);
            acc4 = __builtin_amdgcn_mfma_f32_16x16x32_bf16(A3, B2i, acc4, 0, 0, 0);
            acc4 = __builtin_amdgcn_mfma_f32_16x16x32_bf16(A4, B2r, acc4, 0, 0, 0);
        }
        // C/D: col = lane&15, row = (lane>>4)*4 + r ; rows >=8 are zero pad
        if (kgrp < 2) {
            const int oc = wv * 16 + arow;
#pragma unroll
            for (int r = 0; r < 4; ++r) {
                const int lrow = kgrp * 4 + r;
                yS[(0 * 8 + lrow) * C + oc] = acc0[r];
                yS[(1 * 8 + lrow) * C + oc] = acc1[r];
                yS[(2 * 8 + lrow) * C + oc] = acc2[r];
                yS[(3 * 8 + lrow) * C + oc] = acc3[r];
                yS[(4 * 8 + lrow) * C + oc] = acc4[r];
            }
        }
    }
    __syncthreads();

    // ---------------- Phase C ----------------
    const f32x4 u0 = *(const f32x4*)&yS[(0 * 8 + row) * C + i4 * 4];
    const f32x4 a1 = *(const f32x4*)&yS[(1 * 8 + row) * C + i4 * 4];
    const f32x4 b1 = *(const f32x4*)&yS[(2 * 8 + row) * C + i4 * 4];
    const f32x4 a2 = *(const f32x4*)&yS[(3 * 8 + row) * C + i4 * 4];
    const f32x4 b2 = *(const f32x4*)&yS[(4 * 8 + row) * C + i4 * 4];
    f32x4* op = (f32x4*)out + (size_t)(brow + row) * 32 + i4;
#pragma unroll
    for (int tt = 0; tt < 16; ++tt) {
        int t = tb + tt;
        float c1 = COS32[t], s1 = SIN32[t];
        float c2 = COS32[(2 * t) & 31], s2 = SIN32[(2 * t) & 31];
        f32x4 hv = v[tt];
        f32x4 y = u0 + c1 * a1 - s1 * b1 + c2 * a2 - s2 * b2;
        f32x4 r;
#pragma unroll
        for (int j = 0; j < 4; ++j)
            r[j] = hv[j] + fmaxf(y[j], 0.f) + 0.2f * fminf(y[j], 0.f);
        op[(size_t)t * NBC4] = r;
    }
}

// ---------------------------------------------------------------------------
// Workspace: only Wfrag (160 KiB) at offset 0.
// ---------------------------------------------------------------------------
extern "C" void kernel_launch(void* const* d_in, const int* in_sizes, int n_in,
                              void* d_out, int out_size, void* d_ws, size_t ws_size,
                              hipStream_t stream) {
    const float* h = (const float*)d_in[0];
    const float* wr = (const float*)d_in[1];
    const float* wi = (const float*)d_in[2];
    float* out = (float*)d_out;
    unsigned short* Wfrag = (unsigned short*)d_ws;

    k_wfrag<<<40, 256, 0, stream>>>(wr, wi, Wfrag);
    k_main<<<BN / 8, 512, 0, stream>>>(h, Wfrag, out);
}